// Round 22
// baseline (117.300 us; speedup 1.0000x reference)
//
#include <hip/hip_runtime.h>
#include <math.h>

// Problem constants (match reference)
#define FIN   128
#define HC1   128   // H*C for layer 1
#define NCLS  16
#define NEG_SLOPE 0.2f

typedef __attribute__((ext_vector_type(8))) short bf16x8;
typedef __attribute__((ext_vector_type(4))) float f32x4;
typedef __attribute__((ext_vector_type(2))) float f32x2;

__device__ __forceinline__ unsigned short f2bf_rne(float f) {
    unsigned int u = __float_as_uint(f);
    unsigned int r = u + 0x7FFFu + ((u >> 16) & 1u);
    return (unsigned short)(r >> 16);
}
__device__ __forceinline__ float bf2f(unsigned short h) {
    return __uint_as_float(((unsigned int)h) << 16);
}

// fp8 e4m3 encode via HW converter (round-trips with the decode below).
__device__ __forceinline__ unsigned char f2fp8(float v) {
    int p = __builtin_amdgcn_cvt_pk_fp8_f32(v, v, 0, false);
    return (unsigned char)(p & 0xFF);
}

#define EPB 4096   // edges per block in bcnt/binA  (EB = ceil(E/EPB) must be <=256)

// ---------------------------------------------------------------------------
// gemm1 body, single-bf16 MFMA: h1 = x@W1 -> fp8 e4m3 + fused alpha1.
// ---------------------------------------------------------------------------
__device__ __forceinline__
void gemm1_body(const float* __restrict__ x, const float* __restrict__ W,
                const float* __restrict__ a_src, const float* __restrict__ a_dst,
                unsigned char* __restrict__ h1q, float* __restrict__ as1,
                float* __restrict__ ad1, int N, int bid, float4* smem) {
    unsigned short* whi = (unsigned short*)smem;          // 32 KB, fragment-ordered
    int tid = threadIdx.x;

#pragma unroll
    for (int i = 0; i < 64; ++i) {
        int idx = tid + i * 256;            // 0..16383, coalesced
        int k = idx >> 7, c = idx & 127;
        float v = W[idx];
        unsigned short hb = f2bf_rne(v);
        int kb = k >> 5, kk = k & 31;
        int g = kk >> 3, j = kk & 7;
        int ct = c >> 4, li = c & 15;
        int off = ((kb * 8 + ct) * 64 + g * 16 + li) * 8 + j;
        whi[off] = hb;
    }

    int wid = tid >> 6, lane = tid & 63;
    int li = lane & 15, g = lane >> 4;
    int rowbase = bid * 64 + wid * 16;

    int arow = rowbase + li;
    if (arow >= N) arow = N - 1;            // clamp; invalid rows never stored
    const float* xp = x + (long)arow * FIN + g * 8;
    bf16x8 Ahi[4];
#pragma unroll
    for (int kb = 0; kb < 4; ++kb) {
        float4 v0 = *reinterpret_cast<const float4*>(xp + kb * 32);
        float4 v1 = *reinterpret_cast<const float4*>(xp + kb * 32 + 4);
        bf16x8 h8;
        h8[0] = (short)f2bf_rne(v0.x); h8[1] = (short)f2bf_rne(v0.y);
        h8[2] = (short)f2bf_rne(v0.z); h8[3] = (short)f2bf_rne(v0.w);
        h8[4] = (short)f2bf_rne(v1.x); h8[5] = (short)f2bf_rne(v1.y);
        h8[6] = (short)f2bf_rne(v1.z); h8[7] = (short)f2bf_rne(v1.w);
        Ahi[kb] = h8;
    }

    float asr[8], adr[8];
#pragma unroll
    for (int ct = 0; ct < 8; ++ct) {
        asr[ct] = a_src[ct * 16 + li];
        adr[ct] = a_dst[ct * 16 + li];
    }

    __syncthreads();

    f32x4 acc[8];
#pragma unroll
    for (int ct = 0; ct < 8; ++ct) acc[ct] = (f32x4){0.f, 0.f, 0.f, 0.f};

#pragma unroll
    for (int kb = 0; kb < 4; ++kb) {
#pragma unroll
        for (int ct = 0; ct < 8; ++ct) {
            bf16x8 bh = *reinterpret_cast<const bf16x8*>(&whi[((kb * 8 + ct) * 64 + lane) * 8]);
            acc[ct] = __builtin_amdgcn_mfma_f32_16x16x32_bf16(Ahi[kb], bh, acc[ct], 0, 0, 0);
        }
    }

#pragma unroll
    for (int q = 0; q < 4; ++q) {
        int n = rowbase + g * 4 + q;
        bool valid = (n < N);
        float p0s = 0.f, p1s = 0.f, p0d = 0.f, p1d = 0.f;
#pragma unroll
        for (int ct = 0; ct < 8; ++ct) {
            float h = acc[ct][q];
            if (valid) h1q[(long)n * HC1 + ct * 16 + li] = f2fp8(h);
            if (ct < 4) { p0s = fmaf(h, asr[ct], p0s); p0d = fmaf(h, adr[ct], p0d); }
            else        { p1s = fmaf(h, asr[ct], p1s); p1d = fmaf(h, adr[ct], p1d); }
        }
#pragma unroll
        for (int off = 8; off >= 1; off >>= 1) {
            p0s += __shfl_xor(p0s, off, 16);
            p1s += __shfl_xor(p1s, off, 16);
            p0d += __shfl_xor(p0d, off, 16);
            p1d += __shfl_xor(p1d, off, 16);
        }
        if (valid && li == 0) {
            as1[n * 2 + 0] = p0s; as1[n * 2 + 1] = p1s;
            ad1[n * 2 + 0] = p0d; ad1[n * 2 + 1] = p1d;
        }
    }
}

// ---------------------------------------------------------------------------
// FUSED CSR-build kernels. f_colscan now also performs the bucket scan +
// W2 prep via a last-block-done trick (removes the bscan2 launch).
// ---------------------------------------------------------------------------
__global__ __launch_bounds__(256)
void f_bcnt(const int* __restrict__ ei, int* __restrict__ blockhist, int E, int NB,
            const float* __restrict__ x, const float* __restrict__ W1,
            const float* __restrict__ a_src, const float* __restrict__ a_dst,
            unsigned char* __restrict__ h1q, float* __restrict__ as1,
            float* __restrict__ ad1, int N, int nb_csr, int gemm_base,
            int* __restrict__ donecnt) {
    __shared__ float4 smem[2048];   // 32 KB shared scratch
    int tid = threadIdx.x;
    if ((int)blockIdx.x >= nb_csr) {
        gemm1_body(x, W1, a_src, a_dst, h1q, as1, ad1, N,
                   gemm_base + blockIdx.x - nb_csr, smem);
        return;
    }
    if (blockIdx.x == 0 && tid == 0) donecnt[0] = 0;   // reset for colscan
    int* h = (int*)smem;
    h[tid] = 0;
    __syncthreads();
    int base = blockIdx.x * EPB;
#pragma unroll
    for (int j = 0; j < EPB / 256; ++j) {
        int e = base + j * 256 + tid;
        if (e < E) atomicAdd(&h[ei[E + e] >> 8], 1);
    }
    __syncthreads();
    if (tid < NB) blockhist[blockIdx.x * NB + tid] = h[tid];
}

__global__ __launch_bounds__(256)
void f_colscan(int* __restrict__ blockhist, int* __restrict__ colsum, int EB, int NB,
               int* __restrict__ bucket_base, const float* __restrict__ W2,
               const float* __restrict__ a_src2, const float* __restrict__ a_dst2,
               float* __restrict__ w2T, float* __restrict__ w2s,
               float* __restrict__ w2d, int* __restrict__ donecnt,
               const float* __restrict__ x, const float* __restrict__ W1,
               const float* __restrict__ a_src, const float* __restrict__ a_dst,
               unsigned char* __restrict__ h1q, float* __restrict__ as1,
               float* __restrict__ ad1, int N, int nb_csr, int gemm_base) {
    __shared__ float4 smem[2048];
    __shared__ int lastflag;
    int t = threadIdx.x;
    if ((int)blockIdx.x >= nb_csr) {
        gemm1_body(x, W1, a_src, a_dst, h1q, as1, ad1, N,
                   gemm_base + blockIdx.x - nb_csr, smem);
        return;
    }
    int* lds = (int*)smem;
    int col = blockIdx.x;     // bucket (column)
    int v = (t < EB) ? blockhist[t * NB + col] : 0;
    lds[t] = v;
    __syncthreads();
    for (int off = 1; off < 256; off <<= 1) {
        int u = (t >= off) ? lds[t - off] : 0;
        __syncthreads();
        lds[t] += u;
        __syncthreads();
    }
    if (t < EB) blockhist[t * NB + col] = lds[t] - v;   // excl offset within bucket
    if (t == 255) colsum[col] = lds[255];

    // Last-block-done: the final CSR block performs the bucket scan + W2 prep.
    __threadfence();
    if (t == 0) {
        int old = atomicAdd(donecnt, 1);
        lastflag = (old == NB - 1);
    }
    __syncthreads();
    if (!lastflag) return;

    int cv = (t < NB) ? colsum[t] : 0;
    lds[t] = cv;
    __syncthreads();
    for (int off = 1; off < 256; off <<= 1) {
        int u = (t >= off) ? lds[t - off] : 0;
        __syncthreads();
        lds[t] += u;
        __syncthreads();
    }
    if (t < NB) bucket_base[t] = lds[t] - cv;
    if (t == 255) bucket_base[NB] = lds[255];   // == E

    if (t < FIN) {
        float s = 0.f, d = 0.f;
#pragma unroll
        for (int c = 0; c < NCLS; ++c) {
            float w = W2[t * NCLS + c];
            w2T[c * FIN + t] = w;
            s = fmaf(w, a_src2[c], s);
            d = fmaf(w, a_dst2[c], d);
        }
        w2s[t] = s; w2d[t] = d;
    }
}

__global__ __launch_bounds__(256)
void f_binA(const int* __restrict__ ei, const int* __restrict__ blockhist,
            const int* __restrict__ bucket_base, int* __restrict__ tmp,
            int E, int NB,
            const float* __restrict__ x, const float* __restrict__ W1,
            const float* __restrict__ a_src, const float* __restrict__ a_dst,
            unsigned char* __restrict__ h1q, float* __restrict__ as1,
            float* __restrict__ ad1, int N, int nb_csr, int gemm_base) {
    __shared__ float4 smem[2048];
    int tid = threadIdx.x;
    if ((int)blockIdx.x >= nb_csr) {
        gemm1_body(x, W1, a_src, a_dst, h1q, as1, ad1, N,
                   gemm_base + blockIdx.x - nb_csr, smem);
        return;
    }
    int* h  = (int*)smem;        // local cursors [256]
    int* bb = h + 256;           // global base per bucket [256]
    h[tid] = 0;
    if (tid < NB) bb[tid] = blockhist[blockIdx.x * NB + tid] + bucket_base[tid];
    __syncthreads();
    int base = blockIdx.x * EPB;
#pragma unroll
    for (int j = 0; j < EPB / 256; ++j) {
        int e = base + j * 256 + tid;
        if (e < E) {
            int s = ei[e], d = ei[E + e];
            int b = d >> 8;
            int r = atomicAdd(&h[b], 1);
            tmp[bb[b] + r] = (s << 8) | (d & 255);   // packed
        }
    }
}

__global__ __launch_bounds__(256)
void f_binB(const int* __restrict__ tmp, const int* __restrict__ bucket_base,
            int* __restrict__ csr, int* __restrict__ eoffs, int E, int N,
            const float* __restrict__ x, const float* __restrict__ W1,
            const float* __restrict__ a_src, const float* __restrict__ a_dst,
            unsigned char* __restrict__ h1q, float* __restrict__ as1,
            float* __restrict__ ad1, int nb_csr, int gemm_base) {
    __shared__ float4 smem[2048];
    int t = threadIdx.x;
    if ((int)blockIdx.x >= nb_csr) {
        gemm1_body(x, W1, a_src, a_dst, h1q, as1, ad1, N,
                   gemm_base + blockIdx.x - nb_csr, smem);
        return;
    }
    int* cnt = (int*)smem;       // [256]
    int* lds = cnt + 256;        // [256]
    int* cur = cnt + 512;        // [256]
    int b = blockIdx.x;
    int lo = bucket_base[b], hi = bucket_base[b + 1];
    cnt[t] = 0;
    __syncthreads();
    for (int i = lo + t; i < hi; i += 256)
        atomicAdd(&cnt[tmp[i] & 255], 1);
    __syncthreads();
    int v = cnt[t];
    lds[t] = v;
    __syncthreads();
    for (int off = 1; off < 256; off <<= 1) {
        int u = (t >= off) ? lds[t - off] : 0;
        __syncthreads();
        lds[t] += u;
        __syncthreads();
    }
    int excl = lds[t] - v;
    int node = b * 256 + t;
    if (node < N) eoffs[node] = lo + excl;
    if (b == 0 && t == 0) eoffs[N] = E;
    cur[t] = lo + excl;
    __syncthreads();
    for (int i = lo + t; i < hi; i += 256) {
        int e = tmp[i];
        int p = atomicAdd(&cur[e & 255], 1);
        csr[p] = ((unsigned int)e) >> 8;     // src
    }
}

// ---------------------------------------------------------------------------
// Layer 1 FUSED gather+softmax+ELU+GEMM2+alpha2 over fp8 h1 rows:
// two-phase per 64-edge chunk (score dedup via LDS). Unchanged from R19.
// ---------------------------------------------------------------------------
#define CH 64   // edges per LDS chunk (fgather1)

__global__ __launch_bounds__(256)
void fgather1(const int* __restrict__ eoffs, const int* __restrict__ csr,
              const float* __restrict__ as_arr, const float* __restrict__ ad_arr,
              const unsigned char* __restrict__ h1q, const float* __restrict__ b1,
              const float* __restrict__ w2T, const float* __restrict__ w2s,
              const float* __restrict__ w2d,
              float* __restrict__ zout, float* __restrict__ as2,
              float* __restrict__ ad2, int N) {
    __shared__ float wbuf[8][2][CH];   // [group][head][edge]  4 KB
    __shared__ int   sbuf[8][CH];      // 2 KB
    int tid = threadIdx.x;
    int g = tid >> 5;                // 0..7 node-group in block (32-lane aligned)
    int l = tid & 31;                // lane in group: cols 4l..4l+3
    int n = blockIdx.x * 8 + g;
    if (n >= N) return;
    int head = l >> 4;
    int hl = l & 15;                 // lane within head-group
    int s0 = eoffs[n], s1 = eoffs[n + 1];

    float ad0 = ad_arr[2 * n], ad1v = ad_arr[2 * n + 1];
    float2 aself = *reinterpret_cast<const float2*>(&as_arr[2 * n]);
    float vs0 = aself.x + ad0;  vs0 = (vs0 >= 0.f) ? vs0 : NEG_SLOPE * vs0;
    float vs1 = aself.y + ad1v; vs1 = (vs1 >= 0.f) ? vs1 : NEG_SLOPE * vs1;
    float adn = head ? ad1v : ad0;

    float ps = __expf(head ? vs1 : vs0);
    unsigned int us = *reinterpret_cast<const unsigned int*>(&h1q[((long)n << 7) + 4 * l]);
    f32x2 slo = __builtin_amdgcn_cvt_pk_f32_fp8(us, false);
    f32x2 shi = __builtin_amdgcn_cvt_pk_f32_fp8(us, true);
    float4 acc;
    acc.x = slo[0] * ps; acc.y = slo[1] * ps;
    acc.z = shi[0] * ps; acc.w = shi[1] * ps;
    float denp = 0.f;   // per-lane partial denominator (reduced at end)

    for (int base = s0; base < s1; base += CH) {
        int cnt = min(CH, s1 - base);
        // Phase A: score each edge once per head; stage w and src in LDS.
        for (int j = hl; j < cnt; j += 16) {
            int s = csr[base + j];
            if (head == 0) sbuf[g][j] = s;
            float av = as_arr[2 * s + head];
            float v = av + adn; v = (v >= 0.f) ? v : NEG_SLOPE * v;
            float w = __expf(v);
            wbuf[g][head][j] = w;
            denp += w;
        }
        // Phase B: gather (broadcast LDS reads of w/s).
        int j = 0;
        for (; j + 4 <= cnt; j += 4) {
            int sa = sbuf[g][j],     sb = sbuf[g][j + 1];
            int sc = sbuf[g][j + 2], sd = sbuf[g][j + 3];
            float wa = wbuf[g][head][j],     wb = wbuf[g][head][j + 1];
            float wc = wbuf[g][head][j + 2], wd = wbuf[g][head][j + 3];
            unsigned int ua = *reinterpret_cast<const unsigned int*>(&h1q[((long)sa << 7) + 4 * l]);
            unsigned int ub = *reinterpret_cast<const unsigned int*>(&h1q[((long)sb << 7) + 4 * l]);
            unsigned int uc = *reinterpret_cast<const unsigned int*>(&h1q[((long)sc << 7) + 4 * l]);
            unsigned int ud = *reinterpret_cast<const unsigned int*>(&h1q[((long)sd << 7) + 4 * l]);
            f32x2 lo, hi;
            lo = __builtin_amdgcn_cvt_pk_f32_fp8(ua, false);
            hi = __builtin_amdgcn_cvt_pk_f32_fp8(ua, true);
            acc.x = fmaf(lo[0], wa, acc.x); acc.y = fmaf(lo[1], wa, acc.y);
            acc.z = fmaf(hi[0], wa, acc.z); acc.w = fmaf(hi[1], wa, acc.w);
            lo = __builtin_amdgcn_cvt_pk_f32_fp8(ub, false);
            hi = __builtin_amdgcn_cvt_pk_f32_fp8(ub, true);
            acc.x = fmaf(lo[0], wb, acc.x); acc.y = fmaf(lo[1], wb, acc.y);
            acc.z = fmaf(hi[0], wb, acc.z); acc.w = fmaf(hi[1], wb, acc.w);
            lo = __builtin_amdgcn_cvt_pk_f32_fp8(uc, false);
            hi = __builtin_amdgcn_cvt_pk_f32_fp8(uc, true);
            acc.x = fmaf(lo[0], wc, acc.x); acc.y = fmaf(lo[1], wc, acc.y);
            acc.z = fmaf(hi[0], wc, acc.z); acc.w = fmaf(hi[1], wc, acc.w);
            lo = __builtin_amdgcn_cvt_pk_f32_fp8(ud, false);
            hi = __builtin_amdgcn_cvt_pk_f32_fp8(ud, true);
            acc.x = fmaf(lo[0], wd, acc.x); acc.y = fmaf(lo[1], wd, acc.y);
            acc.z = fmaf(hi[0], wd, acc.z); acc.w = fmaf(hi[1], wd, acc.w);
        }
        for (; j < cnt; ++j) {
            int s = sbuf[g][j];
            float w = wbuf[g][head][j];
            unsigned int u = *reinterpret_cast<const unsigned int*>(&h1q[((long)s << 7) + 4 * l]);
            f32x2 lo = __builtin_amdgcn_cvt_pk_f32_fp8(u, false);
            f32x2 hi = __builtin_amdgcn_cvt_pk_f32_fp8(u, true);
            acc.x = fmaf(lo[0], w, acc.x); acc.y = fmaf(lo[1], w, acc.y);
            acc.z = fmaf(hi[0], w, acc.z); acc.w = fmaf(hi[1], w, acc.w);
        }
    }

    // Reduce partial denominators within each 16-lane head group; add self.
    float den = denp;
#pragma unroll
    for (int off = 8; off >= 1; off >>= 1) den += __shfl_xor(den, off, 16);
    den += ps;

    float r = 1.f / (den + 1e-16f);
    int col = 4 * l;
    float4 bb = *reinterpret_cast<const float4*>(&b1[col]);
    float4 o;
    o.x = acc.x * r + bb.x; o.y = acc.y * r + bb.y;
    o.z = acc.z * r + bb.z; o.w = acc.w * r + bb.w;
    o.x = (o.x > 0.f) ? o.x : expm1f(o.x);
    o.y = (o.y > 0.f) ? o.y : expm1f(o.y);
    o.z = (o.z > 0.f) ? o.z : expm1f(o.z);
    o.w = (o.w > 0.f) ? o.w : expm1f(o.w);

    // as2/ad2 = h2 . (W2 @ a_src2), h2 . (W2 @ a_dst2)  -- 10 shfl
    float4 ws4 = *reinterpret_cast<const float4*>(&w2s[col]);
    float4 wd4 = *reinterpret_cast<const float4*>(&w2d[col]);
    float sa2 = o.x * ws4.x + o.y * ws4.y + o.z * ws4.z + o.w * ws4.w;
    float da2 = o.x * wd4.x + o.y * wd4.y + o.z * wd4.z + o.w * wd4.w;
#pragma unroll
    for (int off = 16; off >= 1; off >>= 1) {
        sa2 += __shfl_xor(sa2, off, 32);
        da2 += __shfl_xor(da2, off, 32);
    }
    if (l == 0) { as2[n] = sa2; ad2[n] = da2; }

    // z = h2 @ W2 via class-fold butterfly (16 shfl total).
    float zp[NCLS];
#pragma unroll
    for (int c = 0; c < NCLS; ++c) {
        float4 w4 = *reinterpret_cast<const float4*>(&w2T[c * FIN + col]);
        zp[c] = o.x * w4.x + o.y * w4.y + o.z * w4.z + o.w * w4.w;
    }
    int bsel = (l >> 4) & 1;
    float z8[8];
#pragma unroll
    for (int j = 0; j < 8; ++j) {
        float send = bsel ? zp[j] : zp[j + 8];
        float keep = bsel ? zp[j + 8] : zp[j];
        z8[j] = keep + __shfl_xor(send, 16, 32);
    }
    bsel = (l >> 3) & 1;
    float z4v[4];
#pragma unroll
    for (int j = 0; j < 4; ++j) {
        float send = bsel ? z8[j] : z8[j + 4];
        float keep = bsel ? z8[j + 4] : z8[j];
        z4v[j] = keep + __shfl_xor(send, 8, 32);
    }
    bsel = (l >> 2) & 1;
    float z2v[2];
#pragma unroll
    for (int j = 0; j < 2; ++j) {
        float send = bsel ? z4v[j] : z4v[j + 2];
        float keep = bsel ? z4v[j + 2] : z4v[j];
        z2v[j] = keep + __shfl_xor(send, 4, 32);
    }
    bsel = (l >> 1) & 1;
    float z1v;
    {
        float send = bsel ? z2v[0] : z2v[1];
        float keep = bsel ? z2v[1] : z2v[0];
        z1v = keep + __shfl_xor(send, 2, 32);
    }
    z1v += __shfl_xor(z1v, 1, 32);
    if (!(l & 1)) zout[(long)n * NCLS + ((l >> 1) & 15)] = z1v;
}

// ---------------------------------------------------------------------------
// Layer 2 FUSED gather+softmax + bias + log_softmax, two-phase score dedup.
// Unchanged from R20.
// ---------------------------------------------------------------------------
#define CH2 32   // edges per LDS chunk (fgather2)

__global__ __launch_bounds__(256)
void fgather2(const int* __restrict__ eoffs, const int* __restrict__ csr,
              const float* __restrict__ as2, const float* __restrict__ ad2,
              const float* __restrict__ z, const float* __restrict__ b2,
              float* __restrict__ out, int N) {
    __shared__ float wbuf[16][CH2];   // 2 KB
    __shared__ int   sbuf[16][CH2];   // 2 KB
    int g = threadIdx.x >> 4;
    int l = threadIdx.x & 15;
    int n = blockIdx.x * 16 + g;
    if (n >= N) return;
    int s0 = eoffs[n], s1 = eoffs[n + 1];
    float adn = ad2[n];
    float vs = as2[n] + adn; vs = (vs >= 0.f) ? vs : NEG_SLOPE * vs;

    float ps = __expf(vs);
    float acc = ps * z[(long)n * NCLS + l];
    float denp = 0.f;

    for (int base = s0; base < s1; base += CH2) {
        int cnt = min(CH2, s1 - base);
        // Phase A: score each edge once (lane-strided), stage w + src.
        for (int j = l; j < cnt; j += 16) {
            int s = csr[base + j];
            sbuf[g][j] = s;
            float v = as2[s] + adn; v = (v >= 0.f) ? v : NEG_SLOPE * v;
            float w = __expf(v);
            wbuf[g][j] = w;
            denp += w;
        }
        // Phase B: gather z (broadcast LDS reads of w/s).
        int j = 0;
        for (; j + 4 <= cnt; j += 4) {
            int sa = sbuf[g][j],     sb = sbuf[g][j + 1];
            int sc = sbuf[g][j + 2], sd = sbuf[g][j + 3];
            float wa = wbuf[g][j],     wb = wbuf[g][j + 1];
            float wc = wbuf[g][j + 2], wd = wbuf[g][j + 3];
            float za = z[sa * NCLS + l];
            float zb = z[sb * NCLS + l];
            float zc = z[sc * NCLS + l];
            float zd = z[sd * NCLS + l];
            acc = fmaf(za, wa, acc);
            acc = fmaf(zb, wb, acc);
            acc = fmaf(zc, wc, acc);
            acc = fmaf(zd, wd, acc);
        }
        for (; j < cnt; ++j) {
            acc = fmaf(z[sbuf[g][j] * NCLS + l], wbuf[g][j], acc);
        }
    }

    // Reduce partial denominators across the 16 lanes; add self.
    float den = denp;
#pragma unroll
    for (int off = 8; off >= 1; off >>= 1) den += __shfl_xor(den, off, 16);
    den += ps;

    float o = acc / (den + 1e-16f) + b2[l];

    float mx = o;
#pragma unroll
    for (int off = 8; off >= 1; off >>= 1) mx = fmaxf(mx, __shfl_xor(mx, off, 16));
    float ex = __expf(o - mx);
    float sum = ex;
#pragma unroll
    for (int off = 8; off >= 1; off >>= 1) sum += __shfl_xor(sum, off, 16);
    out[(long)n * NCLS + l] = o - mx - __logf(sum);
}

// ---------------------------------------------------------------------------
extern "C" void kernel_launch(void* const* d_in, const int* in_sizes, int n_in,
                              void* d_out, int out_size, void* d_ws, size_t ws_size,
                              hipStream_t stream) {
    const float* x        = (const float*)d_in[0];
    const int*   ei       = (const int*)  d_in[1];
    // d_in[2] = edge_attr (unused by reference)
    const float* W1       = (const float*)d_in[3];
    const float* att_src1 = (const float*)d_in[4];
    const float* att_dst1 = (const float*)d_in[5];
    const float* b1       = (const float*)d_in[6];
    const float* W2       = (const float*)d_in[7];
    const float* att_src2 = (const float*)d_in[8];
    const float* att_dst2 = (const float*)d_in[9];
    const float* b2       = (const float*)d_in[10];
    float* out = (float*)d_out;

    const int N = in_sizes[0] / FIN;        // 50000
    const int E = in_sizes[1] / 2;          // 800000
    const int NB = (N + 255) >> 8;          // 196 buckets
    const int EB = (E + EPB - 1) / EPB;     // 196 edge blocks (<=256)
    const int GB = (N + 63) / 64;           // 782 gemm1 blocks

    // gemm1 block slices fused into the 4 parallel CSR kernels
    int q = GB / 4, rr = GB % 4;
    int g0 = q + (rr > 0 ? 1 : 0);
    int g1 = q + (rr > 1 ? 1 : 0);
    int g2 = q + (rr > 2 ? 1 : 0);
    int g3 = q;
    int b0 = 0, b1o = g0, b2o = g0 + g1, b3o = g0 + g1 + g2;

    // Workspace layout (bytes)
    char* ws = (char*)d_ws;
    size_t off = 0;
    auto alloc = [&](size_t bytes) { char* p = ws + off; off += (bytes + 255) & ~(size_t)255; return p; };
    int*    blockhist     = (int*)  alloc((size_t)EB * NB * 4);
    int*    colsum        = (int*)  alloc((size_t)NB * 4);
    int*    bucket_base   = (int*)  alloc((size_t)(NB + 1) * 4);
    int*    donecnt       = (int*)  alloc(4);
    int*    tmp           = (int*)  alloc((size_t)E * 4);    // packed (src<<8)|dst&255
    int*    csr           = (int*)  alloc((size_t)E * 4);
    int*    eoffs         = (int*)  alloc((size_t)(N + 1) * 4);
    unsigned char* h1q    = (unsigned char*)alloc((size_t)N * HC1);  // fp8 e4m3
    float*  z             = (float*) alloc((size_t)N * NCLS * 4);
    float*  as1           = (float*) alloc((size_t)N * 2 * 4);
    float*  ad1           = (float*) alloc((size_t)N * 2 * 4);
    float*  as2           = (float*) alloc((size_t)N * 4);
    float*  ad2           = (float*) alloc((size_t)N * 4);
    float*  w2T           = (float*) alloc((size_t)NCLS * FIN * 4);
    float*  w2s           = (float*) alloc((size_t)FIN * 4);
    float*  w2d           = (float*) alloc((size_t)FIN * 4);
    (void)ws_size;

    f_bcnt<<<EB + g0, 256, 0, stream>>>(ei, blockhist, E, NB,
        x, W1, att_src1, att_dst1, h1q, as1, ad1, N, EB, b0, donecnt);
    f_colscan<<<NB + g1, 256, 0, stream>>>(blockhist, colsum, EB, NB,
        bucket_base, W2, att_src2, att_dst2, w2T, w2s, w2d, donecnt,
        x, W1, att_src1, att_dst1, h1q, as1, ad1, N, NB, b1o);
    f_binA<<<EB + g2, 256, 0, stream>>>(ei, blockhist, bucket_base, tmp, E, NB,
        x, W1, att_src1, att_dst1, h1q, as1, ad1, N, EB, b2o);
    f_binB<<<NB + g3, 256, 0, stream>>>(tmp, bucket_base, csr, eoffs, E, N,
        x, W1, att_src1, att_dst1, h1q, as1, ad1, NB, b3o);

    fgather1<<<(N + 7) / 8, 256, 0, stream>>>(
        eoffs, csr, as1, ad1, h1q, b1, w2T, w2s, w2d, z, as2, ad2, N);
    fgather2<<<(N + 15) / 16, 256, 0, stream>>>(eoffs, csr, as2, ad2, z, b2, out, N);
}

// Round 23
// 92.546 us; speedup vs baseline: 1.2675x; 1.2675x over previous
//
#include <hip/hip_runtime.h>
#include <math.h>

// Problem constants (match reference)
#define FIN   128
#define HC1   128   // H*C for layer 1
#define NCLS  16
#define NEG_SLOPE 0.2f

typedef __attribute__((ext_vector_type(8))) short bf16x8;
typedef __attribute__((ext_vector_type(4))) float f32x4;
typedef __attribute__((ext_vector_type(2))) float f32x2;

__device__ __forceinline__ unsigned short f2bf_rne(float f) {
    unsigned int u = __float_as_uint(f);
    unsigned int r = u + 0x7FFFu + ((u >> 16) & 1u);
    return (unsigned short)(r >> 16);
}
__device__ __forceinline__ float bf2f(unsigned short h) {
    return __uint_as_float(((unsigned int)h) << 16);
}

// fp8 e4m3 encode via HW converter (round-trips with the decode below).
__device__ __forceinline__ unsigned char f2fp8(float v) {
    int p = __builtin_amdgcn_cvt_pk_fp8_f32(v, v, 0, false);
    return (unsigned char)(p & 0xFF);
}

#define EPB 4096   // edges per block in bcnt/binA  (EB = ceil(E/EPB) must be <=256)

// ---------------------------------------------------------------------------
// gemm1 body, single-bf16 MFMA (h1 is fp8 anyway; bf16 error 0.4% << fp8 3.6%):
// h1 = x@W1 -> fp8 e4m3 + fused alpha1 reductions. 32 MFMA/block, 32 KB LDS.
// ---------------------------------------------------------------------------
__device__ __forceinline__
void gemm1_body(const float* __restrict__ x, const float* __restrict__ W,
                const float* __restrict__ a_src, const float* __restrict__ a_dst,
                unsigned char* __restrict__ h1q, float* __restrict__ as1,
                float* __restrict__ ad1, int N, int bid, float4* smem) {
    unsigned short* whi = (unsigned short*)smem;          // 32 KB, fragment-ordered
    int tid = threadIdx.x;

#pragma unroll
    for (int i = 0; i < 64; ++i) {
        int idx = tid + i * 256;            // 0..16383, coalesced
        int k = idx >> 7, c = idx & 127;
        float v = W[idx];
        unsigned short hb = f2bf_rne(v);
        int kb = k >> 5, kk = k & 31;
        int g = kk >> 3, j = kk & 7;
        int ct = c >> 4, li = c & 15;
        int off = ((kb * 8 + ct) * 64 + g * 16 + li) * 8 + j;
        whi[off] = hb;
    }

    int wid = tid >> 6, lane = tid & 63;
    int li = lane & 15, g = lane >> 4;
    int rowbase = bid * 64 + wid * 16;

    int arow = rowbase + li;
    if (arow >= N) arow = N - 1;            // clamp; invalid rows never stored
    const float* xp = x + (long)arow * FIN + g * 8;
    bf16x8 Ahi[4];
#pragma unroll
    for (int kb = 0; kb < 4; ++kb) {
        float4 v0 = *reinterpret_cast<const float4*>(xp + kb * 32);
        float4 v1 = *reinterpret_cast<const float4*>(xp + kb * 32 + 4);
        bf16x8 h8;
        h8[0] = (short)f2bf_rne(v0.x); h8[1] = (short)f2bf_rne(v0.y);
        h8[2] = (short)f2bf_rne(v0.z); h8[3] = (short)f2bf_rne(v0.w);
        h8[4] = (short)f2bf_rne(v1.x); h8[5] = (short)f2bf_rne(v1.y);
        h8[6] = (short)f2bf_rne(v1.z); h8[7] = (short)f2bf_rne(v1.w);
        Ahi[kb] = h8;
    }

    float asr[8], adr[8];
#pragma unroll
    for (int ct = 0; ct < 8; ++ct) {
        asr[ct] = a_src[ct * 16 + li];
        adr[ct] = a_dst[ct * 16 + li];
    }

    __syncthreads();

    f32x4 acc[8];
#pragma unroll
    for (int ct = 0; ct < 8; ++ct) acc[ct] = (f32x4){0.f, 0.f, 0.f, 0.f};

#pragma unroll
    for (int kb = 0; kb < 4; ++kb) {
#pragma unroll
        for (int ct = 0; ct < 8; ++ct) {
            bf16x8 bh = *reinterpret_cast<const bf16x8*>(&whi[((kb * 8 + ct) * 64 + lane) * 8]);
            acc[ct] = __builtin_amdgcn_mfma_f32_16x16x32_bf16(Ahi[kb], bh, acc[ct], 0, 0, 0);
        }
    }

#pragma unroll
    for (int q = 0; q < 4; ++q) {
        int n = rowbase + g * 4 + q;
        bool valid = (n < N);
        float p0s = 0.f, p1s = 0.f, p0d = 0.f, p1d = 0.f;
#pragma unroll
        for (int ct = 0; ct < 8; ++ct) {
            float h = acc[ct][q];
            if (valid) h1q[(long)n * HC1 + ct * 16 + li] = f2fp8(h);
            if (ct < 4) { p0s = fmaf(h, asr[ct], p0s); p0d = fmaf(h, adr[ct], p0d); }
            else        { p1s = fmaf(h, asr[ct], p1s); p1d = fmaf(h, adr[ct], p1d); }
        }
#pragma unroll
        for (int off = 8; off >= 1; off >>= 1) {
            p0s += __shfl_xor(p0s, off, 16);
            p1s += __shfl_xor(p1s, off, 16);
            p0d += __shfl_xor(p0d, off, 16);
            p1d += __shfl_xor(p1d, off, 16);
        }
        if (valid && li == 0) {
            as1[n * 2 + 0] = p0s; as1[n * 2 + 1] = p1s;
            ad1[n * 2 + 0] = p0d; ad1[n * 2 + 1] = p1d;
        }
    }
}

// ---------------------------------------------------------------------------
// FUSED CSR-build kernels: first nb_csr blocks do the CSR phase, remaining
// blocks run a gemm1 slice. tmp packed: (src<<8)|(dst&255), src < 2^24.
// ---------------------------------------------------------------------------
__global__ __launch_bounds__(256)
void f_bcnt(const int* __restrict__ ei, int* __restrict__ blockhist, int E, int NB,
            const float* __restrict__ x, const float* __restrict__ W1,
            const float* __restrict__ a_src, const float* __restrict__ a_dst,
            unsigned char* __restrict__ h1q, float* __restrict__ as1,
            float* __restrict__ ad1, int N, int nb_csr, int gemm_base) {
    __shared__ float4 smem[2048];   // 32 KB shared scratch
    int tid = threadIdx.x;
    if ((int)blockIdx.x >= nb_csr) {
        gemm1_body(x, W1, a_src, a_dst, h1q, as1, ad1, N,
                   gemm_base + blockIdx.x - nb_csr, smem);
        return;
    }
    int* h = (int*)smem;
    h[tid] = 0;
    __syncthreads();
    int base = blockIdx.x * EPB;
#pragma unroll
    for (int j = 0; j < EPB / 256; ++j) {
        int e = base + j * 256 + tid;
        if (e < E) atomicAdd(&h[ei[E + e] >> 8], 1);
    }
    __syncthreads();
    if (tid < NB) blockhist[blockIdx.x * NB + tid] = h[tid];
}

__global__ __launch_bounds__(256)
void f_colscan(int* __restrict__ blockhist, int* __restrict__ colsum, int EB, int NB,
               const float* __restrict__ x, const float* __restrict__ W1,
               const float* __restrict__ a_src, const float* __restrict__ a_dst,
               unsigned char* __restrict__ h1q, float* __restrict__ as1,
               float* __restrict__ ad1, int N, int nb_csr, int gemm_base) {
    __shared__ float4 smem[2048];
    int b = threadIdx.x;
    if ((int)blockIdx.x >= nb_csr) {
        gemm1_body(x, W1, a_src, a_dst, h1q, as1, ad1, N,
                   gemm_base + blockIdx.x - nb_csr, smem);
        return;
    }
    int* lds = (int*)smem;
    int t = blockIdx.x;       // bucket (column)
    int v = (b < EB) ? blockhist[b * NB + t] : 0;
    lds[b] = v;
    __syncthreads();
    for (int off = 1; off < 256; off <<= 1) {
        int u = (b >= off) ? lds[b - off] : 0;
        __syncthreads();
        lds[b] += u;
        __syncthreads();
    }
    if (b < EB) blockhist[b * NB + t] = lds[b] - v;   // excl offset within bucket
    if (b == 255) colsum[t] = lds[255];
}

// 1 block: exclusive scan of colsum -> bucket_base; + W2 prep.
__global__ __launch_bounds__(256)
void bscan2_kernel(const int* __restrict__ colsum, int* __restrict__ bucket_base,
                   int NB, const float* __restrict__ W2,
                   const float* __restrict__ a_src2, const float* __restrict__ a_dst2,
                   float* __restrict__ w2T, float* __restrict__ w2s,
                   float* __restrict__ w2d) {
    __shared__ int lds[256];
    int t = threadIdx.x;
    int v = (t < NB) ? colsum[t] : 0;
    lds[t] = v;
    __syncthreads();
    for (int off = 1; off < 256; off <<= 1) {
        int u = (t >= off) ? lds[t - off] : 0;
        __syncthreads();
        lds[t] += u;
        __syncthreads();
    }
    if (t < NB) bucket_base[t] = lds[t] - v;
    if (t == 255) bucket_base[NB] = lds[255];   // == E

    if (t < FIN) {
        float s = 0.f, d = 0.f;
#pragma unroll
        for (int c = 0; c < NCLS; ++c) {
            float w = W2[t * NCLS + c];
            w2T[c * FIN + t] = w;
            s = fmaf(w, a_src2[c], s);
            d = fmaf(w, a_dst2[c], d);
        }
        w2s[t] = s; w2d[t] = d;
    }
}

__global__ __launch_bounds__(256)
void f_binA(const int* __restrict__ ei, const int* __restrict__ blockhist,
            const int* __restrict__ bucket_base, int* __restrict__ tmp,
            int E, int NB,
            const float* __restrict__ x, const float* __restrict__ W1,
            const float* __restrict__ a_src, const float* __restrict__ a_dst,
            unsigned char* __restrict__ h1q, float* __restrict__ as1,
            float* __restrict__ ad1, int N, int nb_csr, int gemm_base) {
    __shared__ float4 smem[2048];
    int tid = threadIdx.x;
    if ((int)blockIdx.x >= nb_csr) {
        gemm1_body(x, W1, a_src, a_dst, h1q, as1, ad1, N,
                   gemm_base + blockIdx.x - nb_csr, smem);
        return;
    }
    int* h  = (int*)smem;        // local cursors [256]
    int* bb = h + 256;           // global base per bucket [256]
    h[tid] = 0;
    if (tid < NB) bb[tid] = blockhist[blockIdx.x * NB + tid] + bucket_base[tid];
    __syncthreads();
    int base = blockIdx.x * EPB;
#pragma unroll
    for (int j = 0; j < EPB / 256; ++j) {
        int e = base + j * 256 + tid;
        if (e < E) {
            int s = ei[e], d = ei[E + e];
            int b = d >> 8;
            int r = atomicAdd(&h[b], 1);
            tmp[bb[b] + r] = (s << 8) | (d & 255);   // packed
        }
    }
}

__global__ __launch_bounds__(256)
void f_binB(const int* __restrict__ tmp, const int* __restrict__ bucket_base,
            int* __restrict__ csr, int* __restrict__ eoffs, int E, int N,
            const float* __restrict__ x, const float* __restrict__ W1,
            const float* __restrict__ a_src, const float* __restrict__ a_dst,
            unsigned char* __restrict__ h1q, float* __restrict__ as1,
            float* __restrict__ ad1, int nb_csr, int gemm_base) {
    __shared__ float4 smem[2048];
    int t = threadIdx.x;
    if ((int)blockIdx.x >= nb_csr) {
        gemm1_body(x, W1, a_src, a_dst, h1q, as1, ad1, N,
                   gemm_base + blockIdx.x - nb_csr, smem);
        return;
    }
    int* cnt = (int*)smem;       // [256]
    int* lds = cnt + 256;        // [256]
    int* cur = cnt + 512;        // [256]
    int b = blockIdx.x;
    int lo = bucket_base[b], hi = bucket_base[b + 1];
    cnt[t] = 0;
    __syncthreads();
    for (int i = lo + t; i < hi; i += 256)
        atomicAdd(&cnt[tmp[i] & 255], 1);
    __syncthreads();
    int v = cnt[t];
    lds[t] = v;
    __syncthreads();
    for (int off = 1; off < 256; off <<= 1) {
        int u = (t >= off) ? lds[t - off] : 0;
        __syncthreads();
        lds[t] += u;
        __syncthreads();
    }
    int excl = lds[t] - v;
    int node = b * 256 + t;
    if (node < N) eoffs[node] = lo + excl;
    if (b == 0 && t == 0) eoffs[N] = E;
    cur[t] = lo + excl;
    __syncthreads();
    for (int i = lo + t; i < hi; i += 256) {
        int e = tmp[i];
        int p = atomicAdd(&cur[e & 255], 1);
        csr[p] = ((unsigned int)e) >> 8;     // src
    }
}

// ---------------------------------------------------------------------------
// Layer 1 FUSED gather+softmax+ELU+GEMM2+alpha2 over fp8 h1 rows:
// two-phase per 64-edge chunk (score dedup via LDS). Unchanged from R19.
// ---------------------------------------------------------------------------
#define CH 64   // edges per LDS chunk (fgather1)

__global__ __launch_bounds__(256)
void fgather1(const int* __restrict__ eoffs, const int* __restrict__ csr,
              const float* __restrict__ as_arr, const float* __restrict__ ad_arr,
              const unsigned char* __restrict__ h1q, const float* __restrict__ b1,
              const float* __restrict__ w2T, const float* __restrict__ w2s,
              const float* __restrict__ w2d,
              float* __restrict__ zout, float* __restrict__ as2,
              float* __restrict__ ad2, int N) {
    __shared__ float wbuf[8][2][CH];   // [group][head][edge]  4 KB
    __shared__ int   sbuf[8][CH];      // 2 KB
    int tid = threadIdx.x;
    int g = tid >> 5;                // 0..7 node-group in block (32-lane aligned)
    int l = tid & 31;                // lane in group: cols 4l..4l+3
    int n = blockIdx.x * 8 + g;
    if (n >= N) return;
    int head = l >> 4;
    int hl = l & 15;                 // lane within head-group
    int s0 = eoffs[n], s1 = eoffs[n + 1];

    float ad0 = ad_arr[2 * n], ad1v = ad_arr[2 * n + 1];
    float2 aself = *reinterpret_cast<const float2*>(&as_arr[2 * n]);
    float vs0 = aself.x + ad0;  vs0 = (vs0 >= 0.f) ? vs0 : NEG_SLOPE * vs0;
    float vs1 = aself.y + ad1v; vs1 = (vs1 >= 0.f) ? vs1 : NEG_SLOPE * vs1;
    float adn = head ? ad1v : ad0;

    float ps = __expf(head ? vs1 : vs0);
    unsigned int us = *reinterpret_cast<const unsigned int*>(&h1q[((long)n << 7) + 4 * l]);
    f32x2 slo = __builtin_amdgcn_cvt_pk_f32_fp8(us, false);
    f32x2 shi = __builtin_amdgcn_cvt_pk_f32_fp8(us, true);
    float4 acc;
    acc.x = slo[0] * ps; acc.y = slo[1] * ps;
    acc.z = shi[0] * ps; acc.w = shi[1] * ps;
    float denp = 0.f;   // per-lane partial denominator (reduced at end)

    for (int base = s0; base < s1; base += CH) {
        int cnt = min(CH, s1 - base);
        // Phase A: score each edge once per head; stage w and src in LDS.
        for (int j = hl; j < cnt; j += 16) {
            int s = csr[base + j];
            if (head == 0) sbuf[g][j] = s;
            float av = as_arr[2 * s + head];
            float v = av + adn; v = (v >= 0.f) ? v : NEG_SLOPE * v;
            float w = __expf(v);
            wbuf[g][head][j] = w;
            denp += w;
        }
        // Phase B: gather (broadcast LDS reads of w/s).
        int j = 0;
        for (; j + 4 <= cnt; j += 4) {
            int sa = sbuf[g][j],     sb = sbuf[g][j + 1];
            int sc = sbuf[g][j + 2], sd = sbuf[g][j + 3];
            float wa = wbuf[g][head][j],     wb = wbuf[g][head][j + 1];
            float wc = wbuf[g][head][j + 2], wd = wbuf[g][head][j + 3];
            unsigned int ua = *reinterpret_cast<const unsigned int*>(&h1q[((long)sa << 7) + 4 * l]);
            unsigned int ub = *reinterpret_cast<const unsigned int*>(&h1q[((long)sb << 7) + 4 * l]);
            unsigned int uc = *reinterpret_cast<const unsigned int*>(&h1q[((long)sc << 7) + 4 * l]);
            unsigned int ud = *reinterpret_cast<const unsigned int*>(&h1q[((long)sd << 7) + 4 * l]);
            f32x2 lo, hi;
            lo = __builtin_amdgcn_cvt_pk_f32_fp8(ua, false);
            hi = __builtin_amdgcn_cvt_pk_f32_fp8(ua, true);
            acc.x = fmaf(lo[0], wa, acc.x); acc.y = fmaf(lo[1], wa, acc.y);
            acc.z = fmaf(hi[0], wa, acc.z); acc.w = fmaf(hi[1], wa, acc.w);
            lo = __builtin_amdgcn_cvt_pk_f32_fp8(ub, false);
            hi = __builtin_amdgcn_cvt_pk_f32_fp8(ub, true);
            acc.x = fmaf(lo[0], wb, acc.x); acc.y = fmaf(lo[1], wb, acc.y);
            acc.z = fmaf(hi[0], wb, acc.z); acc.w = fmaf(hi[1], wb, acc.w);
            lo = __builtin_amdgcn_cvt_pk_f32_fp8(uc, false);
            hi = __builtin_amdgcn_cvt_pk_f32_fp8(uc, true);
            acc.x = fmaf(lo[0], wc, acc.x); acc.y = fmaf(lo[1], wc, acc.y);
            acc.z = fmaf(hi[0], wc, acc.z); acc.w = fmaf(hi[1], wc, acc.w);
            lo = __builtin_amdgcn_cvt_pk_f32_fp8(ud, false);
            hi = __builtin_amdgcn_cvt_pk_f32_fp8(ud, true);
            acc.x = fmaf(lo[0], wd, acc.x); acc.y = fmaf(lo[1], wd, acc.y);
            acc.z = fmaf(hi[0], wd, acc.z); acc.w = fmaf(hi[1], wd, acc.w);
        }
        for (; j < cnt; ++j) {
            int s = sbuf[g][j];
            float w = wbuf[g][head][j];
            unsigned int u = *reinterpret_cast<const unsigned int*>(&h1q[((long)s << 7) + 4 * l]);
            f32x2 lo = __builtin_amdgcn_cvt_pk_f32_fp8(u, false);
            f32x2 hi = __builtin_amdgcn_cvt_pk_f32_fp8(u, true);
            acc.x = fmaf(lo[0], w, acc.x); acc.y = fmaf(lo[1], w, acc.y);
            acc.z = fmaf(hi[0], w, acc.z); acc.w = fmaf(hi[1], w, acc.w);
        }
    }

    // Reduce partial denominators within each 16-lane head group; add self.
    float den = denp;
#pragma unroll
    for (int off = 8; off >= 1; off >>= 1) den += __shfl_xor(den, off, 16);
    den += ps;

    float r = 1.f / (den + 1e-16f);
    int col = 4 * l;
    float4 bb = *reinterpret_cast<const float4*>(&b1[col]);
    float4 o;
    o.x = acc.x * r + bb.x; o.y = acc.y * r + bb.y;
    o.z = acc.z * r + bb.z; o.w = acc.w * r + bb.w;
    o.x = (o.x > 0.f) ? o.x : expm1f(o.x);
    o.y = (o.y > 0.f) ? o.y : expm1f(o.y);
    o.z = (o.z > 0.f) ? o.z : expm1f(o.z);
    o.w = (o.w > 0.f) ? o.w : expm1f(o.w);

    // as2/ad2 = h2 . (W2 @ a_src2), h2 . (W2 @ a_dst2)  -- 10 shfl
    float4 ws4 = *reinterpret_cast<const float4*>(&w2s[col]);
    float4 wd4 = *reinterpret_cast<const float4*>(&w2d[col]);
    float sa2 = o.x * ws4.x + o.y * ws4.y + o.z * ws4.z + o.w * ws4.w;
    float da2 = o.x * wd4.x + o.y * wd4.y + o.z * wd4.z + o.w * wd4.w;
#pragma unroll
    for (int off = 16; off >= 1; off >>= 1) {
        sa2 += __shfl_xor(sa2, off, 32);
        da2 += __shfl_xor(da2, off, 32);
    }
    if (l == 0) { as2[n] = sa2; ad2[n] = da2; }

    // z = h2 @ W2 via class-fold butterfly (16 shfl total).
    float zp[NCLS];
#pragma unroll
    for (int c = 0; c < NCLS; ++c) {
        float4 w4 = *reinterpret_cast<const float4*>(&w2T[c * FIN + col]);
        zp[c] = o.x * w4.x + o.y * w4.y + o.z * w4.z + o.w * w4.w;
    }
    int bsel = (l >> 4) & 1;
    float z8[8];
#pragma unroll
    for (int j = 0; j < 8; ++j) {
        float send = bsel ? zp[j] : zp[j + 8];
        float keep = bsel ? zp[j + 8] : zp[j];
        z8[j] = keep + __shfl_xor(send, 16, 32);
    }
    bsel = (l >> 3) & 1;
    float z4v[4];
#pragma unroll
    for (int j = 0; j < 4; ++j) {
        float send = bsel ? z8[j] : z8[j + 4];
        float keep = bsel ? z8[j + 4] : z8[j];
        z4v[j] = keep + __shfl_xor(send, 8, 32);
    }
    bsel = (l >> 2) & 1;
    float z2v[2];
#pragma unroll
    for (int j = 0; j < 2; ++j) {
        float send = bsel ? z4v[j] : z4v[j + 2];
        float keep = bsel ? z4v[j + 2] : z4v[j];
        z2v[j] = keep + __shfl_xor(send, 4, 32);
    }
    bsel = (l >> 1) & 1;
    float z1v;
    {
        float send = bsel ? z2v[0] : z2v[1];
        float keep = bsel ? z2v[1] : z2v[0];
        z1v = keep + __shfl_xor(send, 2, 32);
    }
    z1v += __shfl_xor(z1v, 1, 32);
    if (!(l & 1)) zout[(long)n * NCLS + ((l >> 1) & 15)] = z1v;
}

// ---------------------------------------------------------------------------
// Layer 2 FUSED gather+softmax + bias + log_softmax, two-phase score dedup.
// Unchanged from R20.
// ---------------------------------------------------------------------------
#define CH2 32   // edges per LDS chunk (fgather2)

__global__ __launch_bounds__(256)
void fgather2(const int* __restrict__ eoffs, const int* __restrict__ csr,
              const float* __restrict__ as2, const float* __restrict__ ad2,
              const float* __restrict__ z, const float* __restrict__ b2,
              float* __restrict__ out, int N) {
    __shared__ float wbuf[16][CH2];   // 2 KB
    __shared__ int   sbuf[16][CH2];   // 2 KB
    int g = threadIdx.x >> 4;
    int l = threadIdx.x & 15;
    int n = blockIdx.x * 16 + g;
    if (n >= N) return;
    int s0 = eoffs[n], s1 = eoffs[n + 1];
    float adn = ad2[n];
    float vs = as2[n] + adn; vs = (vs >= 0.f) ? vs : NEG_SLOPE * vs;

    float ps = __expf(vs);
    float acc = ps * z[(long)n * NCLS + l];
    float denp = 0.f;

    for (int base = s0; base < s1; base += CH2) {
        int cnt = min(CH2, s1 - base);
        // Phase A: score each edge once (lane-strided), stage w + src.
        for (int j = l; j < cnt; j += 16) {
            int s = csr[base + j];
            sbuf[g][j] = s;
            float v = as2[s] + adn; v = (v >= 0.f) ? v : NEG_SLOPE * v;
            float w = __expf(v);
            wbuf[g][j] = w;
            denp += w;
        }
        // Phase B: gather z (broadcast LDS reads of w/s).
        int j = 0;
        for (; j + 4 <= cnt; j += 4) {
            int sa = sbuf[g][j],     sb = sbuf[g][j + 1];
            int sc = sbuf[g][j + 2], sd = sbuf[g][j + 3];
            float wa = wbuf[g][j],     wb = wbuf[g][j + 1];
            float wc = wbuf[g][j + 2], wd = wbuf[g][j + 3];
            float za = z[sa * NCLS + l];
            float zb = z[sb * NCLS + l];
            float zc = z[sc * NCLS + l];
            float zd = z[sd * NCLS + l];
            acc = fmaf(za, wa, acc);
            acc = fmaf(zb, wb, acc);
            acc = fmaf(zc, wc, acc);
            acc = fmaf(zd, wd, acc);
        }
        for (; j < cnt; ++j) {
            acc = fmaf(z[sbuf[g][j] * NCLS + l], wbuf[g][j], acc);
        }
    }

    // Reduce partial denominators across the 16 lanes; add self.
    float den = denp;
#pragma unroll
    for (int off = 8; off >= 1; off >>= 1) den += __shfl_xor(den, off, 16);
    den += ps;

    float o = acc / (den + 1e-16f) + b2[l];

    float mx = o;
#pragma unroll
    for (int off = 8; off >= 1; off >>= 1) mx = fmaxf(mx, __shfl_xor(mx, off, 16));
    float ex = __expf(o - mx);
    float sum = ex;
#pragma unroll
    for (int off = 8; off >= 1; off >>= 1) sum += __shfl_xor(sum, off, 16);
    out[(long)n * NCLS + l] = o - mx - __logf(sum);
}

// ---------------------------------------------------------------------------
extern "C" void kernel_launch(void* const* d_in, const int* in_sizes, int n_in,
                              void* d_out, int out_size, void* d_ws, size_t ws_size,
                              hipStream_t stream) {
    const float* x        = (const float*)d_in[0];
    const int*   ei       = (const int*)  d_in[1];
    // d_in[2] = edge_attr (unused by reference)
    const float* W1       = (const float*)d_in[3];
    const float* att_src1 = (const float*)d_in[4];
    const float* att_dst1 = (const float*)d_in[5];
    const float* b1       = (const float*)d_in[6];
    const float* W2       = (const float*)d_in[7];
    const float* att_src2 = (const float*)d_in[8];
    const float* att_dst2 = (const float*)d_in[9];
    const float* b2       = (const float*)d_in[10];
    float* out = (float*)d_out;

    const int N = in_sizes[0] / FIN;        // 50000
    const int E = in_sizes[1] / 2;          // 800000
    const int NB = (N + 255) >> 8;          // 196 buckets
    const int EB = (E + EPB - 1) / EPB;     // 196 edge blocks (<=256)
    const int GB = (N + 63) / 64;           // 782 gemm1 blocks

    // gemm1 block slices fused into the 4 parallel CSR kernels
    int q = GB / 4, rr = GB % 4;
    int g0 = q + (rr > 0 ? 1 : 0);
    int g1 = q + (rr > 1 ? 1 : 0);
    int g2 = q + (rr > 2 ? 1 : 0);
    int g3 = q;
    int b0 = 0, b1o = g0, b2o = g0 + g1, b3o = g0 + g1 + g2;

    // Workspace layout (bytes)
    char* ws = (char*)d_ws;
    size_t off = 0;
    auto alloc = [&](size_t bytes) { char* p = ws + off; off += (bytes + 255) & ~(size_t)255; return p; };
    int*    blockhist     = (int*)  alloc((size_t)EB * NB * 4);
    int*    colsum        = (int*)  alloc((size_t)NB * 4);
    int*    bucket_base   = (int*)  alloc((size_t)(NB + 1) * 4);
    int*    tmp           = (int*)  alloc((size_t)E * 4);    // packed (src<<8)|dst&255
    int*    csr           = (int*)  alloc((size_t)E * 4);
    int*    eoffs         = (int*)  alloc((size_t)(N + 1) * 4);
    unsigned char* h1q    = (unsigned char*)alloc((size_t)N * HC1);  // fp8 e4m3
    float*  z             = (float*) alloc((size_t)N * NCLS * 4);
    float*  as1           = (float*) alloc((size_t)N * 2 * 4);
    float*  ad1           = (float*) alloc((size_t)N * 2 * 4);
    float*  as2           = (float*) alloc((size_t)N * 4);
    float*  ad2           = (float*) alloc((size_t)N * 4);
    float*  w2T           = (float*) alloc((size_t)NCLS * FIN * 4);
    float*  w2s           = (float*) alloc((size_t)FIN * 4);
    float*  w2d           = (float*) alloc((size_t)FIN * 4);
    (void)ws_size;

    f_bcnt<<<EB + g0, 256, 0, stream>>>(ei, blockhist, E, NB,
        x, W1, att_src1, att_dst1, h1q, as1, ad1, N, EB, b0);
    f_colscan<<<NB + g1, 256, 0, stream>>>(blockhist, colsum, EB, NB,
        x, W1, att_src1, att_dst1, h1q, as1, ad1, N, NB, b1o);
    bscan2_kernel<<<1, 256, 0, stream>>>(colsum, bucket_base, NB,
                                         W2, att_src2, att_dst2, w2T, w2s, w2d);
    f_binA<<<EB + g2, 256, 0, stream>>>(ei, blockhist, bucket_base, tmp, E, NB,
        x, W1, att_src1, att_dst1, h1q, as1, ad1, N, EB, b2o);
    f_binB<<<NB + g3, 256, 0, stream>>>(tmp, bucket_base, csr, eoffs, E, N,
        x, W1, att_src1, att_dst1, h1q, as1, ad1, NB, b3o);

    fgather1<<<(N + 7) / 8, 256, 0, stream>>>(
        eoffs, csr, as1, ad1, h1q, b1, w2T, w2s, w2d, z, as2, ad2, N);
    fgather2<<<(N + 15) / 16, 256, 0, stream>>>(eoffs, csr, as2, ad2, z, b2, out, N);
}